// Round 10
// baseline (6275.593 us; speedup 1.0000x reference)
//
#include <hip/hip_runtime.h>
#include <hip/hip_cooperative_groups.h>
#include <math.h>

#define NN 4096
#define DD 2048
#define KTOP 1024
#define CIS_STRIDE 1040   // 1040 mod 32 == 16 -> 2-way LDS bank aliasing (free)
#define PSTRIDE 128       // ulls per P record = 1KB: spread records across L2/L3 slices

// A-word: [mono_val:32][zero:8][inv_idx:12][tag:12]
__device__ __forceinline__ unsigned long long packvit(float v, int idx, int tag) {
  unsigned u = __float_as_uint(v);
  u = (u & 0x80000000u) ? ~u : (u | 0x80000000u);  // monotone float->uint
  unsigned long long inv = (unsigned long long)(4095u - (unsigned)idx);
  return ((unsigned long long)u << 32) | (inv << 12) | (unsigned)tag;
}
__device__ __forceinline__ float unpackv(unsigned long long p) {
  unsigned u = (unsigned)(p >> 32);
  u = (u & 0x80000000u) ? (u & 0x7FFFFFFFu) : ~u;
  return __uint_as_float(u);
}
__device__ __forceinline__ int unpacki(unsigned long long p) {
  return 4095 - (int)((p >> 12) & 0xFFFull);
}

// ---- 1) row L2-normalize + diag of similarity ----
__global__ __launch_bounds__(256) void k_normalize(const float* __restrict__ X,
                                                   float* __restrict__ Xn,
                                                   float* __restrict__ diag) {
  __shared__ float red[4];
  const int row = blockIdx.x;
  const int tid = threadIdx.x;
  const float4* x4 = (const float4*)(X + (size_t)row * DD);
  float4 a = x4[tid];
  float4 b = x4[tid + 256];
  float ss = a.x*a.x + a.y*a.y + a.z*a.z + a.w*a.w
           + b.x*b.x + b.y*b.y + b.z*b.z + b.w*b.w;
  #pragma unroll
  for (int m = 1; m < 64; m <<= 1) ss += __shfl_xor(ss, m, 64);
  if ((tid & 63) == 0) red[tid >> 6] = ss;
  __syncthreads();
  const float tot = red[0] + red[1] + red[2] + red[3];
  const float nrm = sqrtf(tot);
  float4 ya, yb;
  ya.x = a.x / nrm; ya.y = a.y / nrm; ya.z = a.z / nrm; ya.w = a.w / nrm;
  yb.x = b.x / nrm; yb.y = b.y / nrm; yb.z = b.z / nrm; yb.w = b.w / nrm;
  float4* y4 = (float4*)(Xn + (size_t)row * DD);
  y4[tid] = ya; y4[tid + 256] = yb;
  float s2 = ya.x*ya.x + ya.y*ya.y + ya.z*ya.z + ya.w*ya.w
           + yb.x*yb.x + yb.y*yb.y + yb.z*yb.z + yb.w*yb.w;
  #pragma unroll
  for (int m = 1; m < 64; m <<= 1) s2 += __shfl_xor(s2, m, 64);
  __syncthreads();
  if ((tid & 63) == 0) red[tid >> 6] = s2;
  __syncthreads();
  if (tid == 0) diag[row] = red[0] + red[1] + red[2] + red[3];
}

// ---- 2) relevance normalization + initial di2s ----
__global__ __launch_bounds__(256) void k_relprep(const float* __restrict__ attn,
                                                 const float* __restrict__ diag,
                                                 float* __restrict__ rel,
                                                 float* __restrict__ di2s) {
  __shared__ float smn[4], smx[4];
  const int tid = threadIdx.x;
  float amin = INFINITY, amax = -INFINITY;
  for (int n = tid; n < NN; n += 256) {
    float v = attn[n];
    amin = fminf(amin, v);
    amax = fmaxf(amax, v);
  }
  #pragma unroll
  for (int m = 1; m < 64; m <<= 1) {
    amin = fminf(amin, __shfl_xor(amin, m, 64));
    amax = fmaxf(amax, __shfl_xor(amax, m, 64));
  }
  if ((tid & 63) == 0) { smn[tid >> 6] = amin; smx[tid >> 6] = amax; }
  __syncthreads();
  amin = fminf(fminf(smn[0], smn[1]), fminf(smn[2], smn[3]));
  amax = fmaxf(fmaxf(smx[0], smx[1]), fmaxf(smx[2], smx[3]));
  const float denom = amax - amin;
  for (int n = tid; n < NN; n += 256) {
    float r = (amax - attn[n]) + 1e-6f;
    float rl = r / denom;
    rel[n] = rl;
    di2s[n] = (rl * diag[n]) * rl;
  }
}

// ---- 3) K = diag(rel)*(Xn Xn^T)*diag(rel), symmetric ----
__global__ __launch_bounds__(256) void k_syrk(const float* __restrict__ Xn,
                                              const float* __restrict__ rel,
                                              float* __restrict__ Kmat) {
  const int bj = blockIdx.x, bi = blockIdx.y;
  if (bi > bj) return;
  __shared__ float As[32][128];
  __shared__ float Bs[32][128];
  const int tid = threadIdx.x;
  const int tx = tid & 15, ty = tid >> 4;
  float acc[8][8];
  #pragma unroll
  for (int y = 0; y < 8; ++y)
    #pragma unroll
    for (int x = 0; x < 8; ++x) acc[y][x] = 0.f;
  const int row0 = bi * 128, col0 = bj * 128;
  const int lr = tid >> 3;
  const int lk = (tid & 7) * 4;
  for (int kk = 0; kk < DD; kk += 32) {
    __syncthreads();
    #pragma unroll
    for (int it = 0; it < 4; ++it) {
      const int r = lr + it * 32;
      float4 va = *(const float4*)(Xn + (size_t)(row0 + r) * DD + kk + lk);
      As[lk + 0][r] = va.x; As[lk + 1][r] = va.y; As[lk + 2][r] = va.z; As[lk + 3][r] = va.w;
      float4 vb = *(const float4*)(Xn + (size_t)(col0 + r) * DD + kk + lk);
      Bs[lk + 0][r] = vb.x; Bs[lk + 1][r] = vb.y; Bs[lk + 2][r] = vb.z; Bs[lk + 3][r] = vb.w;
    }
    __syncthreads();
    #pragma unroll
    for (int k = 0; k < 32; ++k) {
      float af[8], bf[8];
      *(float4*)&af[0] = *(const float4*)&As[k][ty * 8];
      *(float4*)&af[4] = *(const float4*)&As[k][ty * 8 + 4];
      *(float4*)&bf[0] = *(const float4*)&Bs[k][tx * 8];
      *(float4*)&bf[4] = *(const float4*)&Bs[k][tx * 8 + 4];
      #pragma unroll
      for (int y = 0; y < 8; ++y)
        #pragma unroll
        for (int x = 0; x < 8; ++x) acc[y][x] = fmaf(af[y], bf[x], acc[y][x]);
    }
  }
  float relr[8], relc[8];
  #pragma unroll
  for (int y = 0; y < 8; ++y) relr[y] = rel[row0 + ty * 8 + y];
  #pragma unroll
  for (int x = 0; x < 8; ++x) relc[x] = rel[col0 + tx * 8 + x];
  #pragma unroll
  for (int y = 0; y < 8; ++y) {
    const size_t rbase = (size_t)(row0 + ty * 8 + y) * NN + col0 + tx * 8;
    #pragma unroll
    for (int x = 0; x < 8; ++x)
      Kmat[rbase + x] = (relr[y] * acc[y][x]) * relc[x];
  }
  if (bi != bj) {
    #pragma unroll
    for (int x = 0; x < 8; ++x) {
      const size_t rbase = (size_t)(col0 + tx * 8 + x) * NN + row0 + ty * 8;
      #pragma unroll
      for (int y = 0; y < 8; ++y)
        Kmat[rbase + y] = (relc[x] * acc[y][x]) * relr[y];
    }
  }
}

// ---- 4) persistent greedy loop; wave-split roles:
//   wave 0: poll P (relaxed agent atomics) + argmax + broadcast, then falls
//           straight into the NEXT step's spin (no epilogue work).
//   wave 1 (lanes 0-15): owns di2s registers, computes eis, stores cisT rows
//           (agent atomics), and publishes A/B after an s_waitcnt vmcnt(0)
//           drain (same-wave across steps -> certification chain intact).
//   cj staging: normal cached float4 loads (row j read exactly once ever;
//           lines never previously in any L2 this launch; words <= i-2 are at
//           the coherence point by the tag chain; word i-1 via B payload).
__global__ __launch_bounds__(256) void k_greedy(const float* __restrict__ Kmat,
                                                const float* __restrict__ di2s_in,
                                                float* __restrict__ cisT,
                                                unsigned long long* __restrict__ P,
                                                int* __restrict__ selOut) {
  __shared__ __align__(16) float cisL[16 * CIS_STRIDE];  // 66.5 KB: my 16 columns
  __shared__ __align__(16) float cjL[KTOP];
  __shared__ float sred[16];
  __shared__ int jsh;
  __shared__ float djsh;
  __shared__ float cjlast_sh;
  const int b = blockIdx.x;
  const int tid = threadIdx.x;
  const int lane = tid & 63;
  const int c0 = b * 16;
  const int col = tid >> 4;   // 0..15: which of my 16 columns
  const int tg  = tid & 15;   // 0..15: position within t-group

  // initial publish (tag 0) -- by wave 1, which owns the epilogue chain
  float dreg = -INFINITY;
  if (tid >= 64 && tid < 80) {
    const int l = tid - 64;
    dreg = di2s_in[c0 + l];
    unsigned long long pk = packvit(dreg, c0 + l, 0);
    #pragma unroll
    for (int m = 1; m < 16; m <<= 1) {
      unsigned long long o = __shfl_xor(pk, m, 64);
      if (o > pk) pk = o;
    }
    if (tid == 64) {
      __hip_atomic_store(&P[(size_t)b * PSTRIDE + 0], pk, __ATOMIC_RELAXED, __HIP_MEMORY_SCOPE_AGENT);
      __hip_atomic_store(&P[(size_t)b * PSTRIDE + 1], 0ull, __ATOMIC_RELAXED, __HIP_MEMORY_SCOPE_AGENT);
    }
  }

  for (int i = 0; i < KTOP; ++i) {
    // -- wave 0: fused barrier + argmax --
    if (tid < 64) {
      unsigned long long* slotp = P + (size_t)(i & 1) * 256 * PSTRIDE;
      const unsigned long long tagi = (unsigned long long)(unsigned)i;
      unsigned long long a0, a1, a2, a3, b0, b1, b2, b3;
      unsigned bad;
      do {
        a0 = __hip_atomic_load(&slotp[(size_t)lane * PSTRIDE + 0],         __ATOMIC_RELAXED, __HIP_MEMORY_SCOPE_AGENT);
        b0 = __hip_atomic_load(&slotp[(size_t)lane * PSTRIDE + 1],         __ATOMIC_RELAXED, __HIP_MEMORY_SCOPE_AGENT);
        a1 = __hip_atomic_load(&slotp[(size_t)(lane + 64) * PSTRIDE + 0],  __ATOMIC_RELAXED, __HIP_MEMORY_SCOPE_AGENT);
        b1 = __hip_atomic_load(&slotp[(size_t)(lane + 64) * PSTRIDE + 1],  __ATOMIC_RELAXED, __HIP_MEMORY_SCOPE_AGENT);
        a2 = __hip_atomic_load(&slotp[(size_t)(lane + 128) * PSTRIDE + 0], __ATOMIC_RELAXED, __HIP_MEMORY_SCOPE_AGENT);
        b2 = __hip_atomic_load(&slotp[(size_t)(lane + 128) * PSTRIDE + 1], __ATOMIC_RELAXED, __HIP_MEMORY_SCOPE_AGENT);
        a3 = __hip_atomic_load(&slotp[(size_t)(lane + 192) * PSTRIDE + 0], __ATOMIC_RELAXED, __HIP_MEMORY_SCOPE_AGENT);
        b3 = __hip_atomic_load(&slotp[(size_t)(lane + 192) * PSTRIDE + 1], __ATOMIC_RELAXED, __HIP_MEMORY_SCOPE_AGENT);
        bad = (unsigned)((a0 ^ tagi) | (a1 ^ tagi) | (a2 ^ tagi) | (a3 ^ tagi) |
                         (b0 ^ tagi) | (b1 ^ tagi) | (b2 ^ tagi) | (b3 ^ tagi)) & 0xFFFu;
      } while (bad);
      unsigned long long pk = a0;
      if (a1 > pk) pk = a1;
      if (a2 > pk) pk = a2;
      if (a3 > pk) pk = a3;
      #pragma unroll
      for (int m = 1; m < 64; m <<= 1) {
        unsigned long long o = __shfl_xor(pk, m, 64);
        if (o > pk) pk = o;
      }
      const int j = unpacki(pk);
      const int bw = j >> 4;
      const int grp = bw >> 6, srcl = bw & 63;
      unsigned long long bsel = (grp == 0) ? b0 : (grp == 1) ? b1 : (grp == 2) ? b2 : b3;
      bsel = __shfl(bsel, srcl, 64);
      if (lane == 0) {
        jsh = j;
        djsh = unpackv(pk);
        cjlast_sh = __uint_as_float((unsigned)(bsel >> 32));
        if (b == 0) selOut[i] = j;
      }
    }
    __syncthreads();   // sync1: j known everywhere
    const int j = jsh;
    const float dj = djsh;
    const float cj_last = cjlast_sh;

    // wave 1 issues its Kmat load early (retires under the stage)
    float kjm = 0.f;
    if (tid >= 64 && tid < 80) kjm = Kmat[(size_t)j * NN + c0 + (tid - 64)];

    // stage cj rows 0..i-2 via normal cached float4 loads
    const int n4 = (i + 2) >> 2;   // float4 count covering words [0, i-1)
    const float4* __restrict__ rowj4 = (const float4*)(cisT + (size_t)j * KTOP);
    for (int t4 = tid; t4 < n4; t4 += 256)
      ((float4*)cjL)[t4] = rowj4[t4];
    __syncthreads();   // sync2: cjL ready

    // GEMV from LDS + payload term
    float acc = 0.f;
    for (int t = tg; t < i - 1; t += 16)
      acc = fmaf(cjL[t], cisL[col * CIS_STRIDE + t], acc);
    if (i > 0 && ((unsigned)(i - 1) & 15u) == (unsigned)tg)
      acc = fmaf(cj_last, cisL[col * CIS_STRIDE + (i - 1)], acc);
    #pragma unroll
    for (int m = 1; m < 16; m <<= 1) acc += __shfl_xor(acc, m, 64);
    if (tg == 0) sred[col] = acc;
    __syncthreads();   // sync3: sred ready -> wave 1 epilogue, wave 0 next spin

    // epilogue on wave 1 (lanes 0..15); wave 0 is already polling step i+1
    if (tid >= 64 && tid < 80) {
      const int l = tid - 64;
      const int mm = c0 + l;
      const float e = (kjm - sred[l]) / sqrtf(dj);
      float nd = dreg - e * e;
      if (mm == j) nd = -INFINITY;
      dreg = nd;
      unsigned long long pk2 = packvit(nd, mm, i + 1);
      #pragma unroll
      for (int m = 1; m < 16; m <<= 1) {
        unsigned long long o = __shfl_xor(pk2, m, 64);
        if (o > pk2) pk2 = o;
      }
      const int mloc = (4095 - (int)((pk2 >> 12) & 0xFFFull)) - c0;
      const float ewin = __shfl(e, mloc, 64);
      if (tid == 64) {
        // drain wave-1's prior agent-atomic cisT stores (row i-1) so the tag
        // certifies them at the coherence point. Same wave every step.
        asm volatile("s_waitcnt vmcnt(0)" ::: "memory");
        const size_t rec = ((size_t)((i + 1) & 1) * 256 + b) * PSTRIDE;
        __hip_atomic_store(&P[rec + 0], pk2, __ATOMIC_RELAXED, __HIP_MEMORY_SCOPE_AGENT);
        unsigned long long wb = ((unsigned long long)__float_as_uint(ewin) << 32)
                              | (unsigned long long)(unsigned)(i + 1);
        __hip_atomic_store(&P[rec + 1], wb, __ATOMIC_RELAXED, __HIP_MEMORY_SCOPE_AGENT);
      }
      // row-i stores AFTER publish: off critical path, certified next iter
      __hip_atomic_store((unsigned*)cisT + (size_t)mm * KTOP + i, __float_as_uint(e),
                         __ATOMIC_RELAXED, __HIP_MEMORY_SCOPE_AGENT);
      cisL[l * CIS_STRIDE + i] = e;
    }
  }
}

extern "C" void kernel_launch(void* const* d_in, const int* in_sizes, int n_in,
                              void* d_out, int out_size, void* d_ws, size_t ws_size,
                              hipStream_t stream) {
  (void)in_sizes; (void)n_in; (void)out_size; (void)ws_size;
  const float* X    = (const float*)d_in[0];
  const float* attn = (const float*)d_in[1];
  int* sel = (int*)d_out;

  char* w = (char*)d_ws;
  float* Xn   = (float*)(w);                                    // 32 MB
  float* Kmat = (float*)(w + 33554432ull);                      // 64 MB
  float* cisT = (float*)(w + 33554432ull + 67108864ull);        // 16 MB
  float* rel  = (float*)(w + 117440512ull);                     // 16 KB
  float* di2s = (float*)(w + 117440512ull + 16384ull);          // 16 KB
  float* diag = (float*)(w + 117440512ull + 32768ull);          // 16 KB
  unsigned long long* P = (unsigned long long*)(w + 117440512ull + 49152ull); // 512 KB

  k_normalize<<<dim3(NN), dim3(256), 0, stream>>>(X, Xn, diag);
  k_relprep<<<dim3(1), dim3(256), 0, stream>>>(attn, diag, rel, di2s);
  k_syrk<<<dim3(32, 32), dim3(256), 0, stream>>>(Xn, rel, Kmat);

  // cooperative launch only for the co-residency guarantee; no grid.sync inside
  void* args[] = { (void*)&Kmat, (void*)&di2s, (void*)&cisT, (void*)&P, (void*)&sel };
  hipLaunchCooperativeKernel((void*)k_greedy, dim3(256), dim3(256), args, 0u, stream);
}

// Round 11
// 5533.464 us; speedup vs baseline: 1.1341x; 1.1341x over previous
//
#include <hip/hip_runtime.h>
#include <hip/hip_cooperative_groups.h>
#include <math.h>

#define NN 4096
#define DD 2048
#define KTOP 1024
#define CIS_STRIDE 1040   // 1040 mod 32 == 16 -> 2-way LDS bank aliasing (free)
#define PSTRIDE 128       // ulls per P record = 1KB: spread records across L2/L3 slices

// A-word: [mono_val:32][zero:8][inv_idx:12][tag:12]
__device__ __forceinline__ unsigned long long packvit(float v, int idx, int tag) {
  unsigned u = __float_as_uint(v);
  u = (u & 0x80000000u) ? ~u : (u | 0x80000000u);  // monotone float->uint
  unsigned long long inv = (unsigned long long)(4095u - (unsigned)idx);
  return ((unsigned long long)u << 32) | (inv << 12) | (unsigned)tag;
}
__device__ __forceinline__ float unpackv(unsigned long long p) {
  unsigned u = (unsigned)(p >> 32);
  u = (u & 0x80000000u) ? (u & 0x7FFFFFFFu) : ~u;
  return __uint_as_float(u);
}
__device__ __forceinline__ int unpacki(unsigned long long p) {
  return 4095 - (int)((p >> 12) & 0xFFFull);
}

// ---- 1) row L2-normalize + diag of similarity ----
__global__ __launch_bounds__(256) void k_normalize(const float* __restrict__ X,
                                                   float* __restrict__ Xn,
                                                   float* __restrict__ diag) {
  __shared__ float red[4];
  const int row = blockIdx.x;
  const int tid = threadIdx.x;
  const float4* x4 = (const float4*)(X + (size_t)row * DD);
  float4 a = x4[tid];
  float4 b = x4[tid + 256];
  float ss = a.x*a.x + a.y*a.y + a.z*a.z + a.w*a.w
           + b.x*b.x + b.y*b.y + b.z*b.z + b.w*b.w;
  #pragma unroll
  for (int m = 1; m < 64; m <<= 1) ss += __shfl_xor(ss, m, 64);
  if ((tid & 63) == 0) red[tid >> 6] = ss;
  __syncthreads();
  const float tot = red[0] + red[1] + red[2] + red[3];
  const float nrm = sqrtf(tot);
  float4 ya, yb;
  ya.x = a.x / nrm; ya.y = a.y / nrm; ya.z = a.z / nrm; ya.w = a.w / nrm;
  yb.x = b.x / nrm; yb.y = b.y / nrm; yb.z = b.z / nrm; yb.w = b.w / nrm;
  float4* y4 = (float4*)(Xn + (size_t)row * DD);
  y4[tid] = ya; y4[tid + 256] = yb;
  float s2 = ya.x*ya.x + ya.y*ya.y + ya.z*ya.z + ya.w*ya.w
           + yb.x*yb.x + yb.y*yb.y + yb.z*yb.z + yb.w*yb.w;
  #pragma unroll
  for (int m = 1; m < 64; m <<= 1) s2 += __shfl_xor(s2, m, 64);
  __syncthreads();
  if ((tid & 63) == 0) red[tid >> 6] = s2;
  __syncthreads();
  if (tid == 0) diag[row] = red[0] + red[1] + red[2] + red[3];
}

// ---- 2) relevance normalization + initial di2s ----
__global__ __launch_bounds__(256) void k_relprep(const float* __restrict__ attn,
                                                 const float* __restrict__ diag,
                                                 float* __restrict__ rel,
                                                 float* __restrict__ di2s) {
  __shared__ float smn[4], smx[4];
  const int tid = threadIdx.x;
  float amin = INFINITY, amax = -INFINITY;
  for (int n = tid; n < NN; n += 256) {
    float v = attn[n];
    amin = fminf(amin, v);
    amax = fmaxf(amax, v);
  }
  #pragma unroll
  for (int m = 1; m < 64; m <<= 1) {
    amin = fminf(amin, __shfl_xor(amin, m, 64));
    amax = fmaxf(amax, __shfl_xor(amax, m, 64));
  }
  if ((tid & 63) == 0) { smn[tid >> 6] = amin; smx[tid >> 6] = amax; }
  __syncthreads();
  amin = fminf(fminf(smn[0], smn[1]), fminf(smn[2], smn[3]));
  amax = fmaxf(fmaxf(smx[0], smx[1]), fmaxf(smx[2], smx[3]));
  const float denom = amax - amin;
  for (int n = tid; n < NN; n += 256) {
    float r = (amax - attn[n]) + 1e-6f;
    float rl = r / denom;
    rel[n] = rl;
    di2s[n] = (rl * diag[n]) * rl;
  }
}

// ---- 3) K = diag(rel)*(Xn Xn^T)*diag(rel), symmetric ----
__global__ __launch_bounds__(256) void k_syrk(const float* __restrict__ Xn,
                                              const float* __restrict__ rel,
                                              float* __restrict__ Kmat) {
  const int bj = blockIdx.x, bi = blockIdx.y;
  if (bi > bj) return;
  __shared__ float As[32][128];
  __shared__ float Bs[32][128];
  const int tid = threadIdx.x;
  const int tx = tid & 15, ty = tid >> 4;
  float acc[8][8];
  #pragma unroll
  for (int y = 0; y < 8; ++y)
    #pragma unroll
    for (int x = 0; x < 8; ++x) acc[y][x] = 0.f;
  const int row0 = bi * 128, col0 = bj * 128;
  const int lr = tid >> 3;
  const int lk = (tid & 7) * 4;
  for (int kk = 0; kk < DD; kk += 32) {
    __syncthreads();
    #pragma unroll
    for (int it = 0; it < 4; ++it) {
      const int r = lr + it * 32;
      float4 va = *(const float4*)(Xn + (size_t)(row0 + r) * DD + kk + lk);
      As[lk + 0][r] = va.x; As[lk + 1][r] = va.y; As[lk + 2][r] = va.z; As[lk + 3][r] = va.w;
      float4 vb = *(const float4*)(Xn + (size_t)(col0 + r) * DD + kk + lk);
      Bs[lk + 0][r] = vb.x; Bs[lk + 1][r] = vb.y; Bs[lk + 2][r] = vb.z; Bs[lk + 3][r] = vb.w;
    }
    __syncthreads();
    #pragma unroll
    for (int k = 0; k < 32; ++k) {
      float af[8], bf[8];
      *(float4*)&af[0] = *(const float4*)&As[k][ty * 8];
      *(float4*)&af[4] = *(const float4*)&As[k][ty * 8 + 4];
      *(float4*)&bf[0] = *(const float4*)&Bs[k][tx * 8];
      *(float4*)&bf[4] = *(const float4*)&Bs[k][tx * 8 + 4];
      #pragma unroll
      for (int y = 0; y < 8; ++y)
        #pragma unroll
        for (int x = 0; x < 8; ++x) acc[y][x] = fmaf(af[y], bf[x], acc[y][x]);
    }
  }
  float relr[8], relc[8];
  #pragma unroll
  for (int y = 0; y < 8; ++y) relr[y] = rel[row0 + ty * 8 + y];
  #pragma unroll
  for (int x = 0; x < 8; ++x) relc[x] = rel[col0 + tx * 8 + x];
  #pragma unroll
  for (int y = 0; y < 8; ++y) {
    const size_t rbase = (size_t)(row0 + ty * 8 + y) * NN + col0 + tx * 8;
    #pragma unroll
    for (int x = 0; x < 8; ++x)
      Kmat[rbase + x] = (relr[y] * acc[y][x]) * relc[x];
  }
  if (bi != bj) {
    #pragma unroll
    for (int x = 0; x < 8; ++x) {
      const size_t rbase = (size_t)(col0 + tx * 8 + x) * NN + row0 + ty * 8;
      #pragma unroll
      for (int y = 0; y < 8; ++y)
        Kmat[rbase + y] = (relc[x] * acc[y][x]) * relr[y];
    }
  }
}

// ---- 4) persistent greedy loop. Round-8 ordering (epilogue+publish on wave 0,
// publish BEFORE wave 0 re-enters the poll spin) + round-10 float4 cj staging.
//   spin: wave 0 only, relaxed agent atomics on 1KB-strided records.
//   cj: cached float4 loads (row j read once ever; words <= i-2 certified by
//       the tag chain; word i-1 from the winner's B payload).
//   publish: s_waitcnt vmcnt(0) drain then relaxed A/B stores (same wave each
//       step -> certification chain intact).
__global__ __launch_bounds__(256) void k_greedy(const float* __restrict__ Kmat,
                                                const float* __restrict__ di2s_in,
                                                float* __restrict__ cisT,
                                                unsigned long long* __restrict__ P,
                                                int* __restrict__ selOut) {
  __shared__ __align__(16) float cisL[16 * CIS_STRIDE];  // 66.5 KB: my 16 columns
  __shared__ __align__(16) float cjL[KTOP];
  __shared__ float sred[16];
  __shared__ int jsh;
  __shared__ float djsh;
  __shared__ float cjlast_sh;
  const int b = blockIdx.x;
  const int tid = threadIdx.x;
  const int lane = tid & 63;
  const int c0 = b * 16;
  const int col = tid >> 4;   // 0..15: which of my 16 columns
  const int tg  = tid & 15;   // 0..15: position within t-group

  // initial publish (tag 0) -- wave 0 lanes 0-15 (the epilogue owner)
  float dreg = -INFINITY;
  if (tid < 16) {
    dreg = di2s_in[c0 + tid];
    unsigned long long pk = packvit(dreg, c0 + tid, 0);
    #pragma unroll
    for (int m = 1; m < 16; m <<= 1) {
      unsigned long long o = __shfl_xor(pk, m, 64);
      if (o > pk) pk = o;
    }
    if (tid == 0) {
      __hip_atomic_store(&P[(size_t)b * PSTRIDE + 0], pk, __ATOMIC_RELAXED, __HIP_MEMORY_SCOPE_AGENT);
      __hip_atomic_store(&P[(size_t)b * PSTRIDE + 1], 0ull, __ATOMIC_RELAXED, __HIP_MEMORY_SCOPE_AGENT);
    }
  }

  for (int i = 0; i < KTOP; ++i) {
    // -- wave 0: fused barrier + argmax (publish for step i already done) --
    if (tid < 64) {
      unsigned long long* slotp = P + (size_t)(i & 1) * 256 * PSTRIDE;
      const unsigned long long tagi = (unsigned long long)(unsigned)i;
      unsigned long long a0, a1, a2, a3, b0, b1, b2, b3;
      unsigned bad;
      do {
        a0 = __hip_atomic_load(&slotp[(size_t)lane * PSTRIDE + 0],         __ATOMIC_RELAXED, __HIP_MEMORY_SCOPE_AGENT);
        b0 = __hip_atomic_load(&slotp[(size_t)lane * PSTRIDE + 1],         __ATOMIC_RELAXED, __HIP_MEMORY_SCOPE_AGENT);
        a1 = __hip_atomic_load(&slotp[(size_t)(lane + 64) * PSTRIDE + 0],  __ATOMIC_RELAXED, __HIP_MEMORY_SCOPE_AGENT);
        b1 = __hip_atomic_load(&slotp[(size_t)(lane + 64) * PSTRIDE + 1],  __ATOMIC_RELAXED, __HIP_MEMORY_SCOPE_AGENT);
        a2 = __hip_atomic_load(&slotp[(size_t)(lane + 128) * PSTRIDE + 0], __ATOMIC_RELAXED, __HIP_MEMORY_SCOPE_AGENT);
        b2 = __hip_atomic_load(&slotp[(size_t)(lane + 128) * PSTRIDE + 1], __ATOMIC_RELAXED, __HIP_MEMORY_SCOPE_AGENT);
        a3 = __hip_atomic_load(&slotp[(size_t)(lane + 192) * PSTRIDE + 0], __ATOMIC_RELAXED, __HIP_MEMORY_SCOPE_AGENT);
        b3 = __hip_atomic_load(&slotp[(size_t)(lane + 192) * PSTRIDE + 1], __ATOMIC_RELAXED, __HIP_MEMORY_SCOPE_AGENT);
        bad = (unsigned)((a0 ^ tagi) | (a1 ^ tagi) | (a2 ^ tagi) | (a3 ^ tagi) |
                         (b0 ^ tagi) | (b1 ^ tagi) | (b2 ^ tagi) | (b3 ^ tagi)) & 0xFFFu;
      } while (bad);
      unsigned long long pk = a0;
      if (a1 > pk) pk = a1;
      if (a2 > pk) pk = a2;
      if (a3 > pk) pk = a3;
      #pragma unroll
      for (int m = 1; m < 64; m <<= 1) {
        unsigned long long o = __shfl_xor(pk, m, 64);
        if (o > pk) pk = o;
      }
      const int j = unpacki(pk);
      const int bw = j >> 4;
      const int grp = bw >> 6, srcl = bw & 63;
      unsigned long long bsel = (grp == 0) ? b0 : (grp == 1) ? b1 : (grp == 2) ? b2 : b3;
      bsel = __shfl(bsel, srcl, 64);
      if (lane == 0) {
        jsh = j;
        djsh = unpackv(pk);
        cjlast_sh = __uint_as_float((unsigned)(bsel >> 32));
        if (b == 0) selOut[i] = j;
      }
    }
    __syncthreads();   // sync1: j known everywhere
    const int j = jsh;
    const float dj = djsh;
    const float cj_last = cjlast_sh;

    // epilogue lanes issue Kmat load early (retires under the stage)
    float kjm = 0.f;
    if (tid < 16) kjm = Kmat[(size_t)j * NN + c0 + tid];

    // stage cj rows 0..i-2 via normal cached float4 loads (1 RTT total)
    const int n4 = (i + 2) >> 2;   // float4 count covering words [0, i-1)
    const float4* __restrict__ rowj4 = (const float4*)(cisT + (size_t)j * KTOP);
    for (int t4 = tid; t4 < n4; t4 += 256)
      ((float4*)cjL)[t4] = rowj4[t4];
    __syncthreads();   // sync2: cjL ready

    // GEMV from LDS + payload term
    float acc = 0.f;
    for (int t = tg; t < i - 1; t += 16)
      acc = fmaf(cjL[t], cisL[col * CIS_STRIDE + t], acc);
    if (i > 0 && ((unsigned)(i - 1) & 15u) == (unsigned)tg)
      acc = fmaf(cj_last, cisL[col * CIS_STRIDE + (i - 1)], acc);
    #pragma unroll
    for (int m = 1; m < 16; m <<= 1) acc += __shfl_xor(acc, m, 64);
    if (tg == 0) sred[col] = acc;
    __syncthreads();   // sync3: sred ready

    // epilogue on wave 0 lanes 0..15; publish happens BEFORE wave 0 loops
    // back into the next spin (quiet window for the tag stores to land).
    if (tid < 16) {
      const int mm = c0 + tid;
      const float e = (kjm - sred[tid]) / sqrtf(dj);
      float nd = dreg - e * e;
      if (mm == j) nd = -INFINITY;
      dreg = nd;
      unsigned long long pk2 = packvit(nd, mm, i + 1);
      #pragma unroll
      for (int m = 1; m < 16; m <<= 1) {
        unsigned long long o = __shfl_xor(pk2, m, 64);
        if (o > pk2) pk2 = o;
      }
      const int mloc = (4095 - (int)((pk2 >> 12) & 0xFFFull)) - c0;
      const float ewin = __shfl(e, mloc, 64);
      if (tid == 0) {
        // drain this wave's prior agent-atomic cisT stores (row i-1) so the
        // tag certifies them at the coherence point. Same wave every step.
        asm volatile("s_waitcnt vmcnt(0)" ::: "memory");
        const size_t rec = ((size_t)((i + 1) & 1) * 256 + b) * PSTRIDE;
        __hip_atomic_store(&P[rec + 0], pk2, __ATOMIC_RELAXED, __HIP_MEMORY_SCOPE_AGENT);
        unsigned long long wb = ((unsigned long long)__float_as_uint(ewin) << 32)
                              | (unsigned long long)(unsigned)(i + 1);
        __hip_atomic_store(&P[rec + 1], wb, __ATOMIC_RELAXED, __HIP_MEMORY_SCOPE_AGENT);
      }
      // row-i stores AFTER publish: off critical path, certified next iter
      __hip_atomic_store((unsigned*)cisT + (size_t)mm * KTOP + i, __float_as_uint(e),
                         __ATOMIC_RELAXED, __HIP_MEMORY_SCOPE_AGENT);
      cisL[tid * CIS_STRIDE + i] = e;
    }
  }
}

extern "C" void kernel_launch(void* const* d_in, const int* in_sizes, int n_in,
                              void* d_out, int out_size, void* d_ws, size_t ws_size,
                              hipStream_t stream) {
  (void)in_sizes; (void)n_in; (void)out_size; (void)ws_size;
  const float* X    = (const float*)d_in[0];
  const float* attn = (const float*)d_in[1];
  int* sel = (int*)d_out;

  char* w = (char*)d_ws;
  float* Xn   = (float*)(w);                                    // 32 MB
  float* Kmat = (float*)(w + 33554432ull);                      // 64 MB
  float* cisT = (float*)(w + 33554432ull + 67108864ull);        // 16 MB
  float* rel  = (float*)(w + 117440512ull);                     // 16 KB
  float* di2s = (float*)(w + 117440512ull + 16384ull);          // 16 KB
  float* diag = (float*)(w + 117440512ull + 32768ull);          // 16 KB
  unsigned long long* P = (unsigned long long*)(w + 117440512ull + 49152ull); // 512 KB

  k_normalize<<<dim3(NN), dim3(256), 0, stream>>>(X, Xn, diag);
  k_relprep<<<dim3(1), dim3(256), 0, stream>>>(attn, diag, rel, di2s);
  k_syrk<<<dim3(32, 32), dim3(256), 0, stream>>>(Xn, rel, Kmat);

  // cooperative launch only for the co-residency guarantee; no grid.sync inside
  void* args[] = { (void*)&Kmat, (void*)&di2s, (void*)&cisT, (void*)&P, (void*)&sel };
  hipLaunchCooperativeKernel((void*)k_greedy, dim3(256), dim3(256), args, 0u, stream);
}